// Round 3
// baseline (128.357 us; speedup 1.0000x reference)
//
#include <hip/hip_runtime.h>
#include <math.h>

#define N_AA    20
#define NATOM   15
#define TM      32
#define MAXBL   16384
#define MAXBLK  (MAXBL / TM + N_AA)   // 532
#define NWAVE   16
#define NSORT   16                    // parallel sorter blocks
#define MAGIC   0x3FA9C1B7            // non-byte-replicated flag value

#define FSX  104   // feat LDS stride (bf16)
#define HSX  264   // hA stride (bf16)
#define H2SX 136   // hB stride (bf16)

typedef __attribute__((ext_vector_type(8))) short bf16x8;
typedef __attribute__((ext_vector_type(4))) float f32x4;

#define W1F_SLOTS  (N_AA * 16 * 3 * 64)   // 61440 fragment slots (8 bf16 each)
#define W2F_SLOTS  (8 * 8 * 64)           // 4096
#define W34F_SLOTS (8 * 4 * 64)           // 2048
#define TOT_SLOTS  (W1F_SLOTS + W2F_SLOTS + 2 * W34F_SLOTS)  // 69632

__device__ __forceinline__ unsigned short f2bf(float x) {
    unsigned u = __float_as_uint(x);
    return (unsigned short)((u + 0x7FFFu + ((u >> 16) & 1u)) >> 16);   // RNE
}
__device__ __forceinline__ float bf2f(unsigned short h) {
    return __uint_as_float(((unsigned)h) << 16);
}
__device__ __forceinline__ void put2(unsigned short* H, unsigned short* L, int idx, float v) {
    unsigned short hi = f2bf(v);
    H[idx] = hi;
    L[idx] = f2bf(v - bf2f(hi));
}

// ---------------- prep: blocks 0..7 tables, 8..23 parallel sort, 24.. weight packing ----------------
__global__ __launch_bounds__(1024) void prep_kernel(
    const int* __restrict__ seq, const float* __restrict__ aa_emb,
    const float* __restrict__ chain_emb, const float* __restrict__ W1,
    const float* __restrict__ W2, const float* __restrict__ W3, const float* __restrict__ W4,
    int BL,
    float* __restrict__ aaT, float* __restrict__ chT,
    int* __restrict__ bucket_start, int* __restrict__ blk_type,
    int* __restrict__ blk_chunk, int* __restrict__ rowidx,
    int* __restrict__ bhist, int* __restrict__ bdone, int* __restrict__ ready,
    unsigned short* __restrict__ W1fH, unsigned short* __restrict__ W1fL,
    unsigned short* __restrict__ W2fH, unsigned short* __restrict__ W2fL,
    unsigned short* __restrict__ W3fH, unsigned short* __restrict__ W3fL,
    unsigned short* __restrict__ W4fH, unsigned short* __restrict__ W4fL)
{
    const int t = threadIdx.x;
    const int b = blockIdx.x;

    if (b < 8) {                        // aaT / chT tables (fp32), 4 tables per block
        const int tab = b * 4 + (t >> 8);
        const int col = t & 255;
        if (tab < 30) {
            if (tab < N_AA) {
                const float* e = aa_emb + tab * 128;
                float acc = 0.f;
                #pragma unroll 8
                for (int k = 0; k < 128; ++k)
                    acc += e[k] * W1[(size_t)k * 256 + col];
                aaT[tab * 256 + col] = acc;
            } else {
                const int c = tab - N_AA;
                const float* e = chain_emb + c * 128;
                float acc = 0.f;
                #pragma unroll 8
                for (int k = 0; k < 128; ++k)
                    acc += e[k] * W1[(size_t)(1067 + k) * 256 + col];
                chT[c * 256 + col] = acc;
            }
        }
        return;
    }

    if (b >= 8 + NSORT) {               // weight fragment packing (bf16 hi/lo)
        const int slot = (b - 8 - NSORT) * 1024 + t;
        if (slot >= TOT_SLOTS) return;
        float v[8];
        unsigned short *dH, *dL;
        if (slot < W1F_SLOTS) {
            const int g = slot / 3072, r1 = slot % 3072;
            const int tile = r1 / 192, chunk = (r1 / 64) % 3, lane = r1 % 64;
            const int n  = tile * 16 + (lane & 15);
            const int kb = chunk * 32 + (lane >> 4) * 8;
            #pragma unroll
            for (int j = 0; j < 8; ++j) {
                const int k = kb + j;
                float x = 0.f;
                if (k < 45)       x = W1[(size_t)(128 + g * 45 + k) * 256 + n];
                else if (k < 84)  x = W1[(size_t)(1028 + k - 45) * 256 + n];
                v[j] = x;
            }
            dH = W1fH + (size_t)slot * 8; dL = W1fL + (size_t)slot * 8;
        } else if (slot < W1F_SLOTS + W2F_SLOTS) {
            const int s = slot - W1F_SLOTS;
            const int tile = s / 512, chunk = (s / 64) % 8, lane = s % 64;
            const int n  = tile * 16 + (lane & 15);
            const int kb = chunk * 32 + (lane >> 4) * 8;
            #pragma unroll
            for (int j = 0; j < 8; ++j) v[j] = W2[(size_t)(kb + j) * 128 + n];
            dH = W2fH + (size_t)s * 8; dL = W2fL + (size_t)s * 8;
        } else if (slot < W1F_SLOTS + W2F_SLOTS + W34F_SLOTS) {
            const int s = slot - W1F_SLOTS - W2F_SLOTS;
            const int tile = s / 256, chunk = (s / 64) % 4, lane = s % 64;
            const int n  = tile * 16 + (lane & 15);
            const int kb = chunk * 32 + (lane >> 4) * 8;
            #pragma unroll
            for (int j = 0; j < 8; ++j) v[j] = W3[(size_t)(kb + j) * 128 + n];
            dH = W3fH + (size_t)s * 8; dL = W3fL + (size_t)s * 8;
        } else {
            const int s = slot - W1F_SLOTS - W2F_SLOTS - W34F_SLOTS;
            const int tile = s / 256, chunk = (s / 64) % 4, lane = s % 64;
            const int n  = tile * 16 + (lane & 15);
            const int kb = chunk * 32 + (lane >> 4) * 8;
            #pragma unroll
            for (int j = 0; j < 8; ++j) v[j] = W4[(size_t)(kb + j) * 128 + n];
            dH = W4fH + (size_t)s * 8; dL = W4fL + (size_t)s * 8;
        }
        #pragma unroll
        for (int j = 0; j < 8; ++j) {
            const unsigned short hi = f2bf(v[j]);
            dH[j] = hi;
            dL[j] = f2bf(v[j] - bf2f(hi));
        }
        return;
    }

    // ---- blocks 8..23: parallel counting sort (16 sorter blocks) ----
    // Protocol: each sorter publishes its per-bin histogram + MAGIC done-flag;
    // sorter 15 waits for all, does the 20-bin scan + blk tables, publishes ready;
    // all sorters then compute exclusive bases and scatter conflict-free.
    // All 92 prep blocks are co-resident (2 blocks/CU cap * 256 CUs >> 92) -> no deadlock.
    // Stale-flag hazard is benign: published values are input-determined and identical
    // across iterations; poison pattern cannot equal non-byte-replicated MAGIC.
    {
        const int sb = b - 8;
        const int rows_per = (BL + NSORT - 1) / NSORT;      // 1024 for BL=16384
        const int r0 = sb * rows_per;
        const int r1 = min(BL, r0 + rows_per);

        __shared__ int whist[NWAVE][N_AA];
        __shared__ int wcur[NWAVE][N_AA];
        __shared__ int bs_s[N_AA + 1], blkoff_s[N_AA + 1];

        const int w = t >> 6;
        if (t < NWAVE * N_AA) whist[t / N_AA][t % N_AA] = 0;
        __syncthreads();

        int myg[2], myrow[2], nmine = 0;
        for (int i = r0 + t; i < r1; i += 1024) {
            const int gg = seq[i];
            myg[nmine] = gg; myrow[nmine] = i; ++nmine;
            atomicAdd(&whist[w][gg], 1);
        }
        __syncthreads();

        if (t < N_AA) {
            int s = 0;
            #pragma unroll
            for (int ww = 0; ww < NWAVE; ++ww) s += whist[ww][t];
            bhist[sb * N_AA + t] = s;
            __threadfence();
        }
        __syncthreads();
        if (t == 0) atomicExch(&bdone[sb], MAGIC);

        if (sb == NSORT - 1) {
            // scan block: wait for all histograms, then scan + tables
            if (t == 0) {
                for (int bb = 0; bb < NSORT; ++bb)
                    while (__hip_atomic_load(&bdone[bb], __ATOMIC_ACQUIRE,
                                             __HIP_MEMORY_SCOPE_AGENT) != MAGIC)
                        __builtin_amdgcn_s_sleep(8);
                int runr = 0, runb = 0;
                for (int g2 = 0; g2 < N_AA; ++g2) {
                    int s = 0;
                    for (int bb = 0; bb < NSORT; ++bb) s += bhist[bb * N_AA + g2];
                    bs_s[g2] = runr; runr += s;
                    blkoff_s[g2] = runb; runb += (s + TM - 1) / TM;
                }
                bs_s[N_AA] = runr; blkoff_s[N_AA] = runb;
            }
            __syncthreads();
            if (t <= N_AA) bucket_start[t] = bs_s[t];
            const int nblk = blkoff_s[N_AA];
            for (int i = t; i < MAXBLK; i += 1024) {
                if (i < nblk) {
                    int g2 = 0;
                    while (blkoff_s[g2 + 1] <= i) ++g2;
                    blk_type[i]  = g2;
                    blk_chunk[i] = i - blkoff_s[g2];
                } else blk_type[i] = -1;
            }
            __threadfence();
            __syncthreads();
            if (t == 0) atomicExch(ready, MAGIC);
        }

        // all sorter threads: acquire-spin on ready (per-thread acquire -> own L1 coherent)
        while (__hip_atomic_load(ready, __ATOMIC_ACQUIRE, __HIP_MEMORY_SCOPE_AGENT) != MAGIC)
            __builtin_amdgcn_s_sleep(8);

        // exclusive bases: bs[g] + sum_{b'<sb} bhist[b'][g] + sum_{w'<w} whist[w'][g]
        if (t < NWAVE * N_AA) {
            const int w2 = t / N_AA, g2 = t % N_AA;
            int o = bucket_start[g2];
            for (int bb = 0; bb < sb; ++bb) o += bhist[bb * N_AA + g2];
            for (int ww = 0; ww < w2; ++ww) o += whist[ww][g2];
            wcur[w2][g2] = o;
        }
        __syncthreads();
        for (int m = 0; m < nmine; ++m) {
            const int pos = atomicAdd(&wcur[w][myg[m]], 1);
            rowidx[pos] = myrow[m];
        }
        return;
    }
}

// ---------------- fused: features + 4-layer MLP via MFMA, 32 same-type rows/block ----------------
// 256 threads (4 waves), 3 blocks/CU co-resident (LDS 51.6 KB); B-fragments shared across two
// 16-row A tiles; chunk-0 weight fragments of each layer prefetched across the preceding barrier.
__global__ __launch_bounds__(256, 3) void fused_kernel(
    const int* __restrict__ chain_idx, const float* __restrict__ xyz,
    const float* __restrict__ dihedrals, const float* __restrict__ orientation,
    const float* __restrict__ b1, const float* __restrict__ b2,
    const float* __restrict__ b3, const float* __restrict__ b4,
    const float* __restrict__ aaT, const float* __restrict__ chT,
    const int* __restrict__ bucket_start, const int* __restrict__ blk_type,
    const int* __restrict__ blk_chunk, const int* __restrict__ rowidx,
    const unsigned short* __restrict__ W1fH, const unsigned short* __restrict__ W1fL,
    const unsigned short* __restrict__ W2fH, const unsigned short* __restrict__ W2fL,
    const unsigned short* __restrict__ W3fH, const unsigned short* __restrict__ W3fL,
    const unsigned short* __restrict__ W4fH, const unsigned short* __restrict__ W4fL,
    float* __restrict__ out)
{
    __shared__ __align__(16) unsigned short smemA[2 * TM * HSX];            // hA hi | hA lo (33 KB)
    __shared__ __align__(16) unsigned short smemB[2 * TM * H2SX];           // feat (hi|lo) then hB (hi|lo)
    __shared__ int s_row[TM], s_rowld[TM], s_chain[TM];

    unsigned short* hAH   = smemA;
    unsigned short* hAL   = smemA + TM * HSX;
    unsigned short* featH = smemB;                  // feat dead after layer 1
    unsigned short* featL = smemB + TM * FSX;
    unsigned short* hBH   = smemB;                  // hB written in layer-2 epilogue
    unsigned short* hBL   = smemB + TM * H2SX;

    const int t = threadIdx.x;

    // bijective XCD-chunked swizzle: same-g blocks (shared W1f slice) stay on one XCD's L2
    const int nwg = gridDim.x;
    const int q = nwg >> 3, r = nwg & 7;
    const int xcd = blockIdx.x & 7, loc = blockIdx.x >> 3;
    const int bid = (xcd < r ? xcd * (q + 1) : r * (q + 1) + (xcd - r) * q) + loc;

    const int g = blk_type[bid];
    if (g < 0) return;
    const int chunk  = blk_chunk[bid];
    const int bstart = bucket_start[g] + chunk * TM;
    const int nrows  = min(TM, bucket_start[g + 1] - bstart);

    const int wave = t >> 6, lane = t & 63, quad = lane >> 4, nid = lane & 15;

    // ---- prefetch layer-1 chunk-0 weight fragments (needs only g) before feature phase ----
    bf16x8 p1H[4], p1L[4];
    #pragma unroll
    for (int tt = 0; tt < 4; ++tt) {
        const size_t off = ((size_t)((g * 16 + (wave * 4 + tt)) * 3 + 0) * 64 + lane) * 8;
        p1H[tt] = *(const bf16x8*)(W1fH + off);
        p1L[tt] = *(const bf16x8*)(W1fL + off);
    }

    if (t < TM) {
        const bool valid = (t < nrows);
        const int rl = rowidx[valid ? (bstart + t) : bstart];
        s_row[t]   = valid ? rl : -1;
        s_rowld[t] = rl;
        s_chain[t] = chain_idx[rl];
    }
    __syncthreads();

    // ---- features -> bf16 hi/lo in LDS. k map: 0..44 coords, 45..83 dih, 84..95 zero ----
    for (int i = t; i < TM * NATOM; i += 256) {
        const int rr = i / NATOM, a = i % NATOM;
        const int rl = s_rowld[rr];
        const float* xr = xyz + (size_t)rl * (NATOM * 3);
        const float cax = xr[3], cay = xr[4], caz = xr[5];   // CA_IDX = 1
        const float rx = xr[a*3+0] - cax;
        const float ry = xr[a*3+1] - cay;
        const float rz = xr[a*3+2] - caz;
        const float* O = orientation + (size_t)rl * 9;
        put2(featH, featL, rr * FSX + a*3 + 0, O[0]*rx + O[3]*ry + O[6]*rz);
        put2(featH, featL, rr * FSX + a*3 + 1, O[1]*rx + O[4]*ry + O[7]*rz);
        put2(featH, featL, rr * FSX + a*3 + 2, O[2]*rx + O[5]*ry + O[8]*rz);
    }
    if (t < TM * 3) {
        const int rr = t / 3, d = t % 3;
        const float x = dihedrals[(size_t)s_rowld[rr] * 3 + d];
        const int base = rr * FSX + 45 + d * 13;
        const float F3 = (float)(1.0 / 3.0);
        const float s1 = sinf(x), c1 = cosf(x);
        put2(featH, featL, base + 0, x);
        put2(featH, featL, base + 1, s1);           put2(featH, featL, base + 2, sinf(2.f*x));
        put2(featH, featL, base + 3, sinf(3.f*x));  put2(featH, featL, base + 4, s1);
        put2(featH, featL, base + 5, sinf(0.5f*x)); put2(featH, featL, base + 6, sinf(F3*x));
        put2(featH, featL, base + 7, c1);           put2(featH, featL, base + 8, cosf(2.f*x));
        put2(featH, featL, base + 9, cosf(3.f*x));  put2(featH, featL, base +10, c1);
        put2(featH, featL, base +11, cosf(0.5f*x)); put2(featH, featL, base +12, cosf(F3*x));
    }
    if (t < TM) {
        #pragma unroll
        for (int k = 84; k < 96; ++k) { featH[t * FSX + k] = 0; featL[t * FSX + k] = 0; }
    }
    __syncthreads();

    const f32x4 zero = {0.f, 0.f, 0.f, 0.f};

    bf16x8 p2H[2], p2L[2];   // layer-2 chunk-0 prefetch
    // ---- layer 1: h1[32][256] = relu(feat @ W1g + b1 + aaT + chT); K=96 (3 chunks), 4 col-tiles/wave, 2 row-tiles ----
    {
        f32x4 acc[2][4] = {{zero, zero, zero, zero}, {zero, zero, zero, zero}};   // [rt][tt]
        #pragma unroll
        for (int c = 0; c < 3; ++c) {
            const bf16x8 aH0 = *(const bf16x8*)(featH + nid * FSX + c * 32 + quad * 8);
            const bf16x8 aL0 = *(const bf16x8*)(featL + nid * FSX + c * 32 + quad * 8);
            const bf16x8 aH1 = *(const bf16x8*)(featH + (16 + nid) * FSX + c * 32 + quad * 8);
            const bf16x8 aL1 = *(const bf16x8*)(featL + (16 + nid) * FSX + c * 32 + quad * 8);
            #pragma unroll
            for (int tt = 0; tt < 4; ++tt) {
                bf16x8 bH, bL;
                if (c == 0) { bH = p1H[tt]; bL = p1L[tt]; }
                else {
                    const size_t off = ((size_t)((g * 16 + (wave * 4 + tt)) * 3 + c) * 64 + lane) * 8;
                    bH = *(const bf16x8*)(W1fH + off);
                    bL = *(const bf16x8*)(W1fL + off);
                }
                acc[0][tt] = __builtin_amdgcn_mfma_f32_16x16x32_bf16(aH0, bH, acc[0][tt], 0, 0, 0);
                acc[0][tt] = __builtin_amdgcn_mfma_f32_16x16x32_bf16(aH0, bL, acc[0][tt], 0, 0, 0);
                acc[0][tt] = __builtin_amdgcn_mfma_f32_16x16x32_bf16(aL0, bH, acc[0][tt], 0, 0, 0);
                acc[1][tt] = __builtin_amdgcn_mfma_f32_16x16x32_bf16(aH1, bH, acc[1][tt], 0, 0, 0);
                acc[1][tt] = __builtin_amdgcn_mfma_f32_16x16x32_bf16(aH1, bL, acc[1][tt], 0, 0, 0);
                acc[1][tt] = __builtin_amdgcn_mfma_f32_16x16x32_bf16(aL1, bH, acc[1][tt], 0, 0, 0);
            }
        }
        #pragma unroll
        for (int tt = 0; tt < 2; ++tt) {     // prefetch W2 c0 before epilogue+barrier
            const size_t off = ((size_t)((wave * 2 + tt) * 8 + 0) * 64 + lane) * 8;
            p2H[tt] = *(const bf16x8*)(W2fH + off);
            p2L[tt] = *(const bf16x8*)(W2fL + off);
        }
        #pragma unroll
        for (int tt = 0; tt < 4; ++tt) {
            const int j = (wave * 4 + tt) * 16 + nid;
            const float cb = b1[j] + aaT[g * 256 + j];
            #pragma unroll
            for (int rt = 0; rt < 2; ++rt) {
                #pragma unroll
                for (int rr = 0; rr < 4; ++rr) {
                    const int row = rt * 16 + quad * 4 + rr;
                    float v = acc[rt][tt][rr] + cb + chT[s_chain[row] * 256 + j];
                    v = fmaxf(v, 0.f);
                    put2(hAH, hAL, row * HSX + j, v);
                }
            }
        }
    }
    __syncthreads();   // h1 complete; ALL feat reads done -> hB may overwrite feat region

    bf16x8 p3H[2], p3L[2];   // layer-3 chunk-0 prefetch
    // ---- layer 2: h2[32][128] = relu(h1 @ W2 + b2); K=256 (8 chunks), 2 col-tiles/wave ----
    {
        f32x4 acc[2][2] = {{zero, zero}, {zero, zero}};   // [rt][tt]
        #pragma unroll
        for (int c = 0; c < 8; ++c) {
            const bf16x8 aH0 = *(const bf16x8*)(hAH + nid * HSX + c * 32 + quad * 8);
            const bf16x8 aL0 = *(const bf16x8*)(hAL + nid * HSX + c * 32 + quad * 8);
            const bf16x8 aH1 = *(const bf16x8*)(hAH + (16 + nid) * HSX + c * 32 + quad * 8);
            const bf16x8 aL1 = *(const bf16x8*)(hAL + (16 + nid) * HSX + c * 32 + quad * 8);
            #pragma unroll
            for (int tt = 0; tt < 2; ++tt) {
                bf16x8 bH, bL;
                if (c == 0) { bH = p2H[tt]; bL = p2L[tt]; }
                else {
                    const size_t off = ((size_t)((wave * 2 + tt) * 8 + c) * 64 + lane) * 8;
                    bH = *(const bf16x8*)(W2fH + off);
                    bL = *(const bf16x8*)(W2fL + off);
                }
                acc[0][tt] = __builtin_amdgcn_mfma_f32_16x16x32_bf16(aH0, bH, acc[0][tt], 0, 0, 0);
                acc[0][tt] = __builtin_amdgcn_mfma_f32_16x16x32_bf16(aH0, bL, acc[0][tt], 0, 0, 0);
                acc[0][tt] = __builtin_amdgcn_mfma_f32_16x16x32_bf16(aL0, bH, acc[0][tt], 0, 0, 0);
                acc[1][tt] = __builtin_amdgcn_mfma_f32_16x16x32_bf16(aH1, bH, acc[1][tt], 0, 0, 0);
                acc[1][tt] = __builtin_amdgcn_mfma_f32_16x16x32_bf16(aH1, bL, acc[1][tt], 0, 0, 0);
                acc[1][tt] = __builtin_amdgcn_mfma_f32_16x16x32_bf16(aL1, bH, acc[1][tt], 0, 0, 0);
            }
        }
        #pragma unroll
        for (int tt = 0; tt < 2; ++tt) {     // prefetch W3 c0
            const size_t off = ((size_t)((wave * 2 + tt) * 4 + 0) * 64 + lane) * 8;
            p3H[tt] = *(const bf16x8*)(W3fH + off);
            p3L[tt] = *(const bf16x8*)(W3fL + off);
        }
        // no barrier needed here: hB aliases feat only; feat's last reads were guarded by post-L1 barrier
        #pragma unroll
        for (int tt = 0; tt < 2; ++tt) {
            const int j = (wave * 2 + tt) * 16 + nid;
            const float bb = b2[j];
            #pragma unroll
            for (int rt = 0; rt < 2; ++rt) {
                #pragma unroll
                for (int rr = 0; rr < 4; ++rr) {
                    const int row = rt * 16 + quad * 4 + rr;
                    float v = fmaxf(acc[rt][tt][rr] + bb, 0.f);
                    put2(hBH, hBL, row * H2SX + j, v);
                }
            }
        }
    }
    __syncthreads();

    bf16x8 p4H[2], p4L[2];   // layer-4 chunk-0 prefetch
    // ---- layer 3: h3[32][128] = relu(h2 @ W3 + b3); K=128 (4 chunks) -> hA ----
    {
        f32x4 acc[2][2] = {{zero, zero}, {zero, zero}};
        #pragma unroll
        for (int c = 0; c < 4; ++c) {
            const bf16x8 aH0 = *(const bf16x8*)(hBH + nid * H2SX + c * 32 + quad * 8);
            const bf16x8 aL0 = *(const bf16x8*)(hBL + nid * H2SX + c * 32 + quad * 8);
            const bf16x8 aH1 = *(const bf16x8*)(hBH + (16 + nid) * H2SX + c * 32 + quad * 8);
            const bf16x8 aL1 = *(const bf16x8*)(hBL + (16 + nid) * H2SX + c * 32 + quad * 8);
            #pragma unroll
            for (int tt = 0; tt < 2; ++tt) {
                bf16x8 bH, bL;
                if (c == 0) { bH = p3H[tt]; bL = p3L[tt]; }
                else {
                    const size_t off = ((size_t)((wave * 2 + tt) * 4 + c) * 64 + lane) * 8;
                    bH = *(const bf16x8*)(W3fH + off);
                    bL = *(const bf16x8*)(W3fL + off);
                }
                acc[0][tt] = __builtin_amdgcn_mfma_f32_16x16x32_bf16(aH0, bH, acc[0][tt], 0, 0, 0);
                acc[0][tt] = __builtin_amdgcn_mfma_f32_16x16x32_bf16(aH0, bL, acc[0][tt], 0, 0, 0);
                acc[0][tt] = __builtin_amdgcn_mfma_f32_16x16x32_bf16(aL0, bH, acc[0][tt], 0, 0, 0);
                acc[1][tt] = __builtin_amdgcn_mfma_f32_16x16x32_bf16(aH1, bH, acc[1][tt], 0, 0, 0);
                acc[1][tt] = __builtin_amdgcn_mfma_f32_16x16x32_bf16(aH1, bL, acc[1][tt], 0, 0, 0);
                acc[1][tt] = __builtin_amdgcn_mfma_f32_16x16x32_bf16(aL1, bH, acc[1][tt], 0, 0, 0);
            }
        }
        #pragma unroll
        for (int tt = 0; tt < 2; ++tt) {     // prefetch W4 c0
            const size_t off = ((size_t)((wave * 2 + tt) * 4 + 0) * 64 + lane) * 8;
            p4H[tt] = *(const bf16x8*)(W4fH + off);
            p4L[tt] = *(const bf16x8*)(W4fL + off);
        }
        #pragma unroll
        for (int tt = 0; tt < 2; ++tt) {
            const int j = (wave * 2 + tt) * 16 + nid;
            const float bb = b3[j];
            #pragma unroll
            for (int rt = 0; rt < 2; ++rt) {
                #pragma unroll
                for (int rr = 0; rr < 4; ++rr) {
                    const int row = rt * 16 + quad * 4 + rr;
                    float v = fmaxf(acc[rt][tt][rr] + bb, 0.f);
                    put2(hAH, hAL, row * HSX + j, v);
                }
            }
        }
    }
    __syncthreads();

    // ---- layer 4: out = h3 @ W4 + b4; scatter fp32 to original rows ----
    {
        f32x4 acc[2][2] = {{zero, zero}, {zero, zero}};
        #pragma unroll
        for (int c = 0; c < 4; ++c) {
            const bf16x8 aH0 = *(const bf16x8*)(hAH + nid * HSX + c * 32 + quad * 8);
            const bf16x8 aL0 = *(const bf16x8*)(hAL + nid * HSX + c * 32 + quad * 8);
            const bf16x8 aH1 = *(const bf16x8*)(hAH + (16 + nid) * HSX + c * 32 + quad * 8);
            const bf16x8 aL1 = *(const bf16x8*)(hAL + (16 + nid) * HSX + c * 32 + quad * 8);
            #pragma unroll
            for (int tt = 0; tt < 2; ++tt) {
                bf16x8 bH, bL;
                if (c == 0) { bH = p4H[tt]; bL = p4L[tt]; }
                else {
                    const size_t off = ((size_t)((wave * 2 + tt) * 4 + c) * 64 + lane) * 8;
                    bH = *(const bf16x8*)(W4fH + off);
                    bL = *(const bf16x8*)(W4fL + off);
                }
                acc[0][tt] = __builtin_amdgcn_mfma_f32_16x16x32_bf16(aH0, bH, acc[0][tt], 0, 0, 0);
                acc[0][tt] = __builtin_amdgcn_mfma_f32_16x16x32_bf16(aH0, bL, acc[0][tt], 0, 0, 0);
                acc[0][tt] = __builtin_amdgcn_mfma_f32_16x16x32_bf16(aL0, bH, acc[0][tt], 0, 0, 0);
                acc[1][tt] = __builtin_amdgcn_mfma_f32_16x16x32_bf16(aH1, bH, acc[1][tt], 0, 0, 0);
                acc[1][tt] = __builtin_amdgcn_mfma_f32_16x16x32_bf16(aH1, bL, acc[1][tt], 0, 0, 0);
                acc[1][tt] = __builtin_amdgcn_mfma_f32_16x16x32_bf16(aL1, bH, acc[1][tt], 0, 0, 0);
            }
        }
        #pragma unroll
        for (int tt = 0; tt < 2; ++tt) {
            const int j = (wave * 2 + tt) * 16 + nid;
            const float bb = b4[j];
            #pragma unroll
            for (int rt = 0; rt < 2; ++rt) {
                #pragma unroll
                for (int rr = 0; rr < 4; ++rr) {
                    const int row = rt * 16 + quad * 4 + rr;
                    const int orow = s_row[row];
                    if (orow >= 0) out[(size_t)orow * 128 + j] = acc[rt][tt][rr] + bb;
                }
            }
        }
    }
}

extern "C" void kernel_launch(void* const* d_in, const int* in_sizes, int n_in,
                              void* d_out, int out_size, void* d_ws, size_t ws_size,
                              hipStream_t stream) {
    const int*   seq    = (const int*)d_in[0];
    const float* xyz    = (const float*)d_in[1];
    const float* dihed  = (const float*)d_in[2];
    const int*   chain  = (const int*)d_in[3];
    const float* orient = (const float*)d_in[4];
    // d_in[5] = atom_mask: unused by the reference
    const float* aa_emb = (const float*)d_in[6];
    const float* ch_emb = (const float*)d_in[7];
    const float* W1 = (const float*)d_in[8];
    const float* b1 = (const float*)d_in[9];
    const float* W2 = (const float*)d_in[10];
    const float* b2 = (const float*)d_in[11];
    const float* W3 = (const float*)d_in[12];
    const float* b3 = (const float*)d_in[13];
    const float* W4 = (const float*)d_in[14];
    const float* b4 = (const float*)d_in[15];
    float* out = (float*)d_out;

    const int BL = in_sizes[0];           // 16384 rows

    // workspace layout
    char* p = (char*)d_ws;
    float* aaT = (float*)p;            p += 20 * 256 * 4;
    float* chT = (float*)p;            p += 10 * 256 * 4;
    int* bucket_start = (int*)p;       p += 32 * 4;
    int* blk_type     = (int*)p;       p += MAXBLK * 4;
    int* blk_chunk    = (int*)p;       p += MAXBLK * 4;
    int* rowidx       = (int*)p;       p += MAXBL * 4;
    int* bhist        = (int*)p;       p += NSORT * N_AA * 4;
    int* bdone        = (int*)p;       p += NSORT * 4;
    int* ready        = (int*)p;       p += 16;
    p += ((16 - ((uintptr_t)p & 15)) & 15);
    unsigned short* W1fH = (unsigned short*)p; p += (size_t)W1F_SLOTS * 8 * 2;
    unsigned short* W1fL = (unsigned short*)p; p += (size_t)W1F_SLOTS * 8 * 2;
    unsigned short* W2fH = (unsigned short*)p; p += (size_t)W2F_SLOTS * 8 * 2;
    unsigned short* W2fL = (unsigned short*)p; p += (size_t)W2F_SLOTS * 8 * 2;
    unsigned short* W3fH = (unsigned short*)p; p += (size_t)W34F_SLOTS * 8 * 2;
    unsigned short* W3fL = (unsigned short*)p; p += (size_t)W34F_SLOTS * 8 * 2;
    unsigned short* W4fH = (unsigned short*)p; p += (size_t)W34F_SLOTS * 8 * 2;
    unsigned short* W4fL = (unsigned short*)p;

    const int nprep  = 8 + NSORT + (TOT_SLOTS + 1023) / 1024;    // 92 blocks
    const int nfused = BL / TM + N_AA;                           // 532

    prep_kernel<<<nprep, 1024, 0, stream>>>(seq, aa_emb, ch_emb, W1, W2, W3, W4, BL,
                                            aaT, chT, bucket_start, blk_type, blk_chunk, rowidx,
                                            bhist, bdone, ready,
                                            W1fH, W1fL, W2fH, W2fL, W3fH, W3fL, W4fH, W4fL);
    fused_kernel<<<nfused, 256, 0, stream>>>(chain, xyz, dihed, orient,
                                             b1, b2, b3, b4, aaT, chT,
                                             bucket_start, blk_type, blk_chunk, rowidx,
                                             W1fH, W1fL, W2fH, W2fL, W3fH, W3fL, W4fH, W4fL,
                                             out);
}

// Round 4
// 120.136 us; speedup vs baseline: 1.0684x; 1.0684x over previous
//
#include <hip/hip_runtime.h>
#include <math.h>

#define N_AA    20
#define NATOM   15
#define TM      32
#define MAXBL   16384
#define MAXBLK  (MAXBL / TM + N_AA)   // 532
#define NWAVE   16

#define FSX  104   // feat LDS stride (bf16)
#define HSX  264   // hA stride (bf16)
#define H2SX 136   // hB stride (bf16)

typedef __attribute__((ext_vector_type(8))) short bf16x8;
typedef __attribute__((ext_vector_type(4))) float f32x4;

#define W1F_SLOTS  (N_AA * 16 * 3 * 64)   // 61440 fragment slots (8 bf16 each)
#define W2F_SLOTS  (8 * 8 * 64)           // 4096
#define W34F_SLOTS (8 * 4 * 64)           // 2048
#define TOT_SLOTS  (W1F_SLOTS + W2F_SLOTS + 2 * W34F_SLOTS)  // 69632

__device__ __forceinline__ unsigned short f2bf(float x) {
    unsigned u = __float_as_uint(x);
    return (unsigned short)((u + 0x7FFFu + ((u >> 16) & 1u)) >> 16);   // RNE
}
__device__ __forceinline__ float bf2f(unsigned short h) {
    return __uint_as_float(((unsigned)h) << 16);
}
__device__ __forceinline__ void put2(unsigned short* H, unsigned short* L, int idx, float v) {
    unsigned short hi = f2bf(v);
    H[idx] = hi;
    L[idx] = f2bf(v - bf2f(hi));
}

// ---------------- prep: blocks 0..7 tables (4 each), 8 sort, 9.. weight-fragment packing ----------------
__global__ __launch_bounds__(1024) void prep_kernel(
    const int* __restrict__ seq, const float* __restrict__ aa_emb,
    const float* __restrict__ chain_emb, const float* __restrict__ W1,
    const float* __restrict__ W2, const float* __restrict__ W3, const float* __restrict__ W4,
    int BL,
    float* __restrict__ aaT, float* __restrict__ chT,
    int* __restrict__ bucket_start, int* __restrict__ blk_type,
    int* __restrict__ blk_chunk, int* __restrict__ rowidx,
    unsigned short* __restrict__ W1fH, unsigned short* __restrict__ W1fL,
    unsigned short* __restrict__ W2fH, unsigned short* __restrict__ W2fL,
    unsigned short* __restrict__ W3fH, unsigned short* __restrict__ W3fL,
    unsigned short* __restrict__ W4fH, unsigned short* __restrict__ W4fL)
{
    const int t = threadIdx.x;
    const int b = blockIdx.x;

    if (b < 8) {                        // aaT / chT tables (fp32), 4 tables per block
        const int tab = b * 4 + (t >> 8);
        const int col = t & 255;
        if (tab < 30) {
            if (tab < N_AA) {
                const float* e = aa_emb + tab * 128;
                float acc = 0.f;
                #pragma unroll 8
                for (int k = 0; k < 128; ++k)
                    acc += e[k] * W1[(size_t)k * 256 + col];
                aaT[tab * 256 + col] = acc;
            } else {
                const int c = tab - N_AA;
                const float* e = chain_emb + c * 128;
                float acc = 0.f;
                #pragma unroll 8
                for (int k = 0; k < 128; ++k)
                    acc += e[k] * W1[(size_t)(1067 + k) * 256 + col];
                chT[c * 256 + col] = acc;
            }
        }
        return;
    }

    if (b >= 9) {                       // weight fragment packing (bf16 hi/lo)
        const int slot = (b - 9) * 1024 + t;
        if (slot >= TOT_SLOTS) return;
        float v[8];
        unsigned short *dH, *dL;
        if (slot < W1F_SLOTS) {
            const int g = slot / 3072, r1 = slot % 3072;
            const int tile = r1 / 192, chunk = (r1 / 64) % 3, lane = r1 % 64;
            const int n  = tile * 16 + (lane & 15);
            const int kb = chunk * 32 + (lane >> 4) * 8;
            #pragma unroll
            for (int j = 0; j < 8; ++j) {
                const int k = kb + j;
                float x = 0.f;
                if (k < 45)       x = W1[(size_t)(128 + g * 45 + k) * 256 + n];
                else if (k < 84)  x = W1[(size_t)(1028 + k - 45) * 256 + n];
                v[j] = x;
            }
            dH = W1fH + (size_t)slot * 8; dL = W1fL + (size_t)slot * 8;
        } else if (slot < W1F_SLOTS + W2F_SLOTS) {
            const int s = slot - W1F_SLOTS;
            const int tile = s / 512, chunk = (s / 64) % 8, lane = s % 64;
            const int n  = tile * 16 + (lane & 15);
            const int kb = chunk * 32 + (lane >> 4) * 8;
            #pragma unroll
            for (int j = 0; j < 8; ++j) v[j] = W2[(size_t)(kb + j) * 128 + n];
            dH = W2fH + (size_t)s * 8; dL = W2fL + (size_t)s * 8;
        } else if (slot < W1F_SLOTS + W2F_SLOTS + W34F_SLOTS) {
            const int s = slot - W1F_SLOTS - W2F_SLOTS;
            const int tile = s / 256, chunk = (s / 64) % 4, lane = s % 64;
            const int n  = tile * 16 + (lane & 15);
            const int kb = chunk * 32 + (lane >> 4) * 8;
            #pragma unroll
            for (int j = 0; j < 8; ++j) v[j] = W3[(size_t)(kb + j) * 128 + n];
            dH = W3fH + (size_t)s * 8; dL = W3fL + (size_t)s * 8;
        } else {
            const int s = slot - W1F_SLOTS - W2F_SLOTS - W34F_SLOTS;
            const int tile = s / 256, chunk = (s / 64) % 4, lane = s % 64;
            const int n  = tile * 16 + (lane & 15);
            const int kb = chunk * 32 + (lane >> 4) * 8;
            #pragma unroll
            for (int j = 0; j < 8; ++j) v[j] = W4[(size_t)(kb + j) * 128 + n];
            dH = W4fH + (size_t)s * 8; dL = W4fL + (size_t)s * 8;
        }
        #pragma unroll
        for (int j = 0; j < 8; ++j) {
            const unsigned short hi = f2bf(v[j]);
            dH[j] = hi;
            dL[j] = f2bf(v[j] - bf2f(hi));
        }
        return;
    }

    // ---- block 8: counting sort of rows by aa type (register-resident, single block) ----
    __shared__ int whist[NWAVE][N_AA];
    __shared__ int wcur[NWAVE][N_AA];
    __shared__ int gtot[N_AA];
    __shared__ int bs[N_AA + 1];
    __shared__ int blkoff[N_AA + 1];

    const int w = t >> 6;
    if (t < NWAVE * N_AA) whist[t / N_AA][t % N_AA] = 0;
    __syncthreads();

    // load rows into registers (fully unrolled -> static indices -> VGPRs) + histogram
    int myg[16];
    #pragma unroll
    for (int it = 0; it < 16; ++it) {
        const int i = t + it * 1024;
        if (i < BL) {
            const int gg = seq[i];
            myg[it] = gg;
            atomicAdd(&whist[w][gg], 1);
        }
    }
    __syncthreads();

    // parallel bin reduce (20 threads), then tiny serial prefix scan
    if (t < N_AA) {
        int s = 0;
        #pragma unroll
        for (int ww = 0; ww < NWAVE; ++ww) s += whist[ww][t];
        gtot[t] = s;
    }
    __syncthreads();
    if (t == 0) {
        int runr = 0, runb = 0;
        for (int g = 0; g < N_AA; ++g) {
            const int s = gtot[g];
            bs[g] = runr; runr += s;
            blkoff[g] = runb; runb += (s + TM - 1) / TM;
        }
        bs[N_AA] = runr; blkoff[N_AA] = runb;
    }
    __syncthreads();
    if (t <= N_AA) bucket_start[t] = bs[t];
    if (t < NWAVE * N_AA) {
        const int w2 = t / N_AA, g2 = t % N_AA;
        int o = bs[g2];
        for (int ww = 0; ww < w2; ++ww) o += whist[ww][g2];
        wcur[w2][g2] = o;
    }
    const int nblk = blkoff[N_AA];
    for (int i = t; i < MAXBLK; i += 1024) {
        if (i < nblk) {
            int g = 0;
            while (blkoff[g + 1] <= i) ++g;
            blk_type[i]  = g;
            blk_chunk[i] = i - blkoff[g];
        } else blk_type[i] = -1;
    }
    __syncthreads();

    // scatter from registers (row index recomputed, not stored)
    #pragma unroll
    for (int it = 0; it < 16; ++it) {
        const int i = t + it * 1024;
        if (i < BL) {
            const int pos = atomicAdd(&wcur[w][myg[it]], 1);
            rowidx[pos] = i;
        }
    }
}

// ---------------- fused: features + 4-layer MLP via MFMA, 32 same-type rows/block ----------------
// 256 threads (4 waves), 3 blocks/CU co-resident (LDS 51.6 KB); B-fragments shared across two
// 16-row A tiles; chunk-0 weight fragments of each layer prefetched across the preceding barrier.
__global__ __launch_bounds__(256, 3) void fused_kernel(
    const int* __restrict__ chain_idx, const float* __restrict__ xyz,
    const float* __restrict__ dihedrals, const float* __restrict__ orientation,
    const float* __restrict__ b1, const float* __restrict__ b2,
    const float* __restrict__ b3, const float* __restrict__ b4,
    const float* __restrict__ aaT, const float* __restrict__ chT,
    const int* __restrict__ bucket_start, const int* __restrict__ blk_type,
    const int* __restrict__ blk_chunk, const int* __restrict__ rowidx,
    const unsigned short* __restrict__ W1fH, const unsigned short* __restrict__ W1fL,
    const unsigned short* __restrict__ W2fH, const unsigned short* __restrict__ W2fL,
    const unsigned short* __restrict__ W3fH, const unsigned short* __restrict__ W3fL,
    const unsigned short* __restrict__ W4fH, const unsigned short* __restrict__ W4fL,
    float* __restrict__ out)
{
    __shared__ __align__(16) unsigned short smemA[2 * TM * HSX];            // hA hi | hA lo (33 KB)
    __shared__ __align__(16) unsigned short smemB[2 * TM * H2SX];           // feat (hi|lo) then hB (hi|lo)
    __shared__ int s_row[TM], s_rowld[TM], s_chain[TM];

    unsigned short* hAH   = smemA;
    unsigned short* hAL   = smemA + TM * HSX;
    unsigned short* featH = smemB;                  // feat dead after layer 1
    unsigned short* featL = smemB + TM * FSX;
    unsigned short* hBH   = smemB;                  // hB written in layer-2 epilogue
    unsigned short* hBL   = smemB + TM * H2SX;

    const int t = threadIdx.x;

    // bijective XCD-chunked swizzle: same-g blocks (shared W1f slice) stay on one XCD's L2
    const int nwg = gridDim.x;
    const int q = nwg >> 3, r = nwg & 7;
    const int xcd = blockIdx.x & 7, loc = blockIdx.x >> 3;
    const int bid = (xcd < r ? xcd * (q + 1) : r * (q + 1) + (xcd - r) * q) + loc;

    const int g = blk_type[bid];
    if (g < 0) return;
    const int chunk  = blk_chunk[bid];
    const int bstart = bucket_start[g] + chunk * TM;
    const int nrows  = min(TM, bucket_start[g + 1] - bstart);

    const int wave = t >> 6, lane = t & 63, quad = lane >> 4, nid = lane & 15;

    // ---- prefetch layer-1 chunk-0 weight fragments (needs only g) before feature phase ----
    bf16x8 p1H[4], p1L[4];
    #pragma unroll
    for (int tt = 0; tt < 4; ++tt) {
        const size_t off = ((size_t)((g * 16 + (wave * 4 + tt)) * 3 + 0) * 64 + lane) * 8;
        p1H[tt] = *(const bf16x8*)(W1fH + off);
        p1L[tt] = *(const bf16x8*)(W1fL + off);
    }

    if (t < TM) {
        const bool valid = (t < nrows);
        const int rl = rowidx[valid ? (bstart + t) : bstart];
        s_row[t]   = valid ? rl : -1;
        s_rowld[t] = rl;
        s_chain[t] = chain_idx[rl];
    }
    __syncthreads();

    // ---- features -> bf16 hi/lo in LDS. k map: 0..44 coords, 45..83 dih, 84..95 zero ----
    for (int i = t; i < TM * NATOM; i += 256) {
        const int rr = i / NATOM, a = i % NATOM;
        const int rl = s_rowld[rr];
        const float* xr = xyz + (size_t)rl * (NATOM * 3);
        const float cax = xr[3], cay = xr[4], caz = xr[5];   // CA_IDX = 1
        const float rx = xr[a*3+0] - cax;
        const float ry = xr[a*3+1] - cay;
        const float rz = xr[a*3+2] - caz;
        const float* O = orientation + (size_t)rl * 9;
        put2(featH, featL, rr * FSX + a*3 + 0, O[0]*rx + O[3]*ry + O[6]*rz);
        put2(featH, featL, rr * FSX + a*3 + 1, O[1]*rx + O[4]*ry + O[7]*rz);
        put2(featH, featL, rr * FSX + a*3 + 2, O[2]*rx + O[5]*ry + O[8]*rz);
    }
    if (t < TM * 3) {
        const int rr = t / 3, d = t % 3;
        const float x = dihedrals[(size_t)s_rowld[rr] * 3 + d];
        const int base = rr * FSX + 45 + d * 13;
        const float F3 = (float)(1.0 / 3.0);
        const float s1 = sinf(x), c1 = cosf(x);
        put2(featH, featL, base + 0, x);
        put2(featH, featL, base + 1, s1);           put2(featH, featL, base + 2, sinf(2.f*x));
        put2(featH, featL, base + 3, sinf(3.f*x));  put2(featH, featL, base + 4, s1);
        put2(featH, featL, base + 5, sinf(0.5f*x)); put2(featH, featL, base + 6, sinf(F3*x));
        put2(featH, featL, base + 7, c1);           put2(featH, featL, base + 8, cosf(2.f*x));
        put2(featH, featL, base + 9, cosf(3.f*x));  put2(featH, featL, base +10, c1);
        put2(featH, featL, base +11, cosf(0.5f*x)); put2(featH, featL, base +12, cosf(F3*x));
    }
    if (t < TM) {
        #pragma unroll
        for (int k = 84; k < 96; ++k) { featH[t * FSX + k] = 0; featL[t * FSX + k] = 0; }
    }
    __syncthreads();

    const f32x4 zero = {0.f, 0.f, 0.f, 0.f};

    bf16x8 p2H[2], p2L[2];   // layer-2 chunk-0 prefetch
    // ---- layer 1: h1[32][256] = relu(feat @ W1g + b1 + aaT + chT); K=96 (3 chunks), 4 col-tiles/wave, 2 row-tiles ----
    {
        f32x4 acc[2][4] = {{zero, zero, zero, zero}, {zero, zero, zero, zero}};   // [rt][tt]
        #pragma unroll
        for (int c = 0; c < 3; ++c) {
            const bf16x8 aH0 = *(const bf16x8*)(featH + nid * FSX + c * 32 + quad * 8);
            const bf16x8 aL0 = *(const bf16x8*)(featL + nid * FSX + c * 32 + quad * 8);
            const bf16x8 aH1 = *(const bf16x8*)(featH + (16 + nid) * FSX + c * 32 + quad * 8);
            const bf16x8 aL1 = *(const bf16x8*)(featL + (16 + nid) * FSX + c * 32 + quad * 8);
            #pragma unroll
            for (int tt = 0; tt < 4; ++tt) {
                bf16x8 bH, bL;
                if (c == 0) { bH = p1H[tt]; bL = p1L[tt]; }
                else {
                    const size_t off = ((size_t)((g * 16 + (wave * 4 + tt)) * 3 + c) * 64 + lane) * 8;
                    bH = *(const bf16x8*)(W1fH + off);
                    bL = *(const bf16x8*)(W1fL + off);
                }
                acc[0][tt] = __builtin_amdgcn_mfma_f32_16x16x32_bf16(aH0, bH, acc[0][tt], 0, 0, 0);
                acc[0][tt] = __builtin_amdgcn_mfma_f32_16x16x32_bf16(aH0, bL, acc[0][tt], 0, 0, 0);
                acc[0][tt] = __builtin_amdgcn_mfma_f32_16x16x32_bf16(aL0, bH, acc[0][tt], 0, 0, 0);
                acc[1][tt] = __builtin_amdgcn_mfma_f32_16x16x32_bf16(aH1, bH, acc[1][tt], 0, 0, 0);
                acc[1][tt] = __builtin_amdgcn_mfma_f32_16x16x32_bf16(aH1, bL, acc[1][tt], 0, 0, 0);
                acc[1][tt] = __builtin_amdgcn_mfma_f32_16x16x32_bf16(aL1, bH, acc[1][tt], 0, 0, 0);
            }
        }
        #pragma unroll
        for (int tt = 0; tt < 2; ++tt) {     // prefetch W2 c0 before epilogue+barrier
            const size_t off = ((size_t)((wave * 2 + tt) * 8 + 0) * 64 + lane) * 8;
            p2H[tt] = *(const bf16x8*)(W2fH + off);
            p2L[tt] = *(const bf16x8*)(W2fL + off);
        }
        #pragma unroll
        for (int tt = 0; tt < 4; ++tt) {
            const int j = (wave * 4 + tt) * 16 + nid;
            const float cb = b1[j] + aaT[g * 256 + j];
            #pragma unroll
            for (int rt = 0; rt < 2; ++rt) {
                #pragma unroll
                for (int rr = 0; rr < 4; ++rr) {
                    const int row = rt * 16 + quad * 4 + rr;
                    float v = acc[rt][tt][rr] + cb + chT[s_chain[row] * 256 + j];
                    v = fmaxf(v, 0.f);
                    put2(hAH, hAL, row * HSX + j, v);
                }
            }
        }
    }
    __syncthreads();   // h1 complete; ALL feat reads done -> hB may overwrite feat region

    bf16x8 p3H[2], p3L[2];   // layer-3 chunk-0 prefetch
    // ---- layer 2: h2[32][128] = relu(h1 @ W2 + b2); K=256 (8 chunks), 2 col-tiles/wave ----
    {
        f32x4 acc[2][2] = {{zero, zero}, {zero, zero}};   // [rt][tt]
        #pragma unroll
        for (int c = 0; c < 8; ++c) {
            const bf16x8 aH0 = *(const bf16x8*)(hAH + nid * HSX + c * 32 + quad * 8);
            const bf16x8 aL0 = *(const bf16x8*)(hAL + nid * HSX + c * 32 + quad * 8);
            const bf16x8 aH1 = *(const bf16x8*)(hAH + (16 + nid) * HSX + c * 32 + quad * 8);
            const bf16x8 aL1 = *(const bf16x8*)(hAL + (16 + nid) * HSX + c * 32 + quad * 8);
            #pragma unroll
            for (int tt = 0; tt < 2; ++tt) {
                bf16x8 bH, bL;
                if (c == 0) { bH = p2H[tt]; bL = p2L[tt]; }
                else {
                    const size_t off = ((size_t)((wave * 2 + tt) * 8 + c) * 64 + lane) * 8;
                    bH = *(const bf16x8*)(W2fH + off);
                    bL = *(const bf16x8*)(W2fL + off);
                }
                acc[0][tt] = __builtin_amdgcn_mfma_f32_16x16x32_bf16(aH0, bH, acc[0][tt], 0, 0, 0);
                acc[0][tt] = __builtin_amdgcn_mfma_f32_16x16x32_bf16(aH0, bL, acc[0][tt], 0, 0, 0);
                acc[0][tt] = __builtin_amdgcn_mfma_f32_16x16x32_bf16(aL0, bH, acc[0][tt], 0, 0, 0);
                acc[1][tt] = __builtin_amdgcn_mfma_f32_16x16x32_bf16(aH1, bH, acc[1][tt], 0, 0, 0);
                acc[1][tt] = __builtin_amdgcn_mfma_f32_16x16x32_bf16(aH1, bL, acc[1][tt], 0, 0, 0);
                acc[1][tt] = __builtin_amdgcn_mfma_f32_16x16x32_bf16(aL1, bH, acc[1][tt], 0, 0, 0);
            }
        }
        #pragma unroll
        for (int tt = 0; tt < 2; ++tt) {     // prefetch W3 c0
            const size_t off = ((size_t)((wave * 2 + tt) * 4 + 0) * 64 + lane) * 8;
            p3H[tt] = *(const bf16x8*)(W3fH + off);
            p3L[tt] = *(const bf16x8*)(W3fL + off);
        }
        // no barrier needed here: hB aliases feat only; feat's last reads were guarded by post-L1 barrier
        #pragma unroll
        for (int tt = 0; tt < 2; ++tt) {
            const int j = (wave * 2 + tt) * 16 + nid;
            const float bb = b2[j];
            #pragma unroll
            for (int rt = 0; rt < 2; ++rt) {
                #pragma unroll
                for (int rr = 0; rr < 4; ++rr) {
                    const int row = rt * 16 + quad * 4 + rr;
                    float v = fmaxf(acc[rt][tt][rr] + bb, 0.f);
                    put2(hBH, hBL, row * H2SX + j, v);
                }
            }
        }
    }
    __syncthreads();

    bf16x8 p4H[2], p4L[2];   // layer-4 chunk-0 prefetch
    // ---- layer 3: h3[32][128] = relu(h2 @ W3 + b3); K=128 (4 chunks) -> hA ----
    {
        f32x4 acc[2][2] = {{zero, zero}, {zero, zero}};
        #pragma unroll
        for (int c = 0; c < 4; ++c) {
            const bf16x8 aH0 = *(const bf16x8*)(hBH + nid * H2SX + c * 32 + quad * 8);
            const bf16x8 aL0 = *(const bf16x8*)(hBL + nid * H2SX + c * 32 + quad * 8);
            const bf16x8 aH1 = *(const bf16x8*)(hBH + (16 + nid) * H2SX + c * 32 + quad * 8);
            const bf16x8 aL1 = *(const bf16x8*)(hBL + (16 + nid) * H2SX + c * 32 + quad * 8);
            #pragma unroll
            for (int tt = 0; tt < 2; ++tt) {
                bf16x8 bH, bL;
                if (c == 0) { bH = p3H[tt]; bL = p3L[tt]; }
                else {
                    const size_t off = ((size_t)((wave * 2 + tt) * 4 + c) * 64 + lane) * 8;
                    bH = *(const bf16x8*)(W3fH + off);
                    bL = *(const bf16x8*)(W3fL + off);
                }
                acc[0][tt] = __builtin_amdgcn_mfma_f32_16x16x32_bf16(aH0, bH, acc[0][tt], 0, 0, 0);
                acc[0][tt] = __builtin_amdgcn_mfma_f32_16x16x32_bf16(aH0, bL, acc[0][tt], 0, 0, 0);
                acc[0][tt] = __builtin_amdgcn_mfma_f32_16x16x32_bf16(aL0, bH, acc[0][tt], 0, 0, 0);
                acc[1][tt] = __builtin_amdgcn_mfma_f32_16x16x32_bf16(aH1, bH, acc[1][tt], 0, 0, 0);
                acc[1][tt] = __builtin_amdgcn_mfma_f32_16x16x32_bf16(aH1, bL, acc[1][tt], 0, 0, 0);
                acc[1][tt] = __builtin_amdgcn_mfma_f32_16x16x32_bf16(aL1, bH, acc[1][tt], 0, 0, 0);
            }
        }
        #pragma unroll
        for (int tt = 0; tt < 2; ++tt) {     // prefetch W4 c0
            const size_t off = ((size_t)((wave * 2 + tt) * 4 + 0) * 64 + lane) * 8;
            p4H[tt] = *(const bf16x8*)(W4fH + off);
            p4L[tt] = *(const bf16x8*)(W4fL + off);
        }
        #pragma unroll
        for (int tt = 0; tt < 2; ++tt) {
            const int j = (wave * 2 + tt) * 16 + nid;
            const float bb = b3[j];
            #pragma unroll
            for (int rt = 0; rt < 2; ++rt) {
                #pragma unroll
                for (int rr = 0; rr < 4; ++rr) {
                    const int row = rt * 16 + quad * 4 + rr;
                    float v = fmaxf(acc[rt][tt][rr] + bb, 0.f);
                    put2(hAH, hAL, row * HSX + j, v);
                }
            }
        }
    }
    __syncthreads();

    // ---- layer 4: out = h3 @ W4 + b4; scatter fp32 to original rows ----
    {
        f32x4 acc[2][2] = {{zero, zero}, {zero, zero}};
        #pragma unroll
        for (int c = 0; c < 4; ++c) {
            const bf16x8 aH0 = *(const bf16x8*)(hAH + nid * HSX + c * 32 + quad * 8);
            const bf16x8 aL0 = *(const bf16x8*)(hAL + nid * HSX + c * 32 + quad * 8);
            const bf16x8 aH1 = *(const bf16x8*)(hAH + (16 + nid) * HSX + c * 32 + quad * 8);
            const bf16x8 aL1 = *(const bf16x8*)(hAL + (16 + nid) * HSX + c * 32 + quad * 8);
            #pragma unroll
            for (int tt = 0; tt < 2; ++tt) {
                bf16x8 bH, bL;
                if (c == 0) { bH = p4H[tt]; bL = p4L[tt]; }
                else {
                    const size_t off = ((size_t)((wave * 2 + tt) * 4 + c) * 64 + lane) * 8;
                    bH = *(const bf16x8*)(W4fH + off);
                    bL = *(const bf16x8*)(W4fL + off);
                }
                acc[0][tt] = __builtin_amdgcn_mfma_f32_16x16x32_bf16(aH0, bH, acc[0][tt], 0, 0, 0);
                acc[0][tt] = __builtin_amdgcn_mfma_f32_16x16x32_bf16(aH0, bL, acc[0][tt], 0, 0, 0);
                acc[0][tt] = __builtin_amdgcn_mfma_f32_16x16x32_bf16(aL0, bH, acc[0][tt], 0, 0, 0);
                acc[1][tt] = __builtin_amdgcn_mfma_f32_16x16x32_bf16(aH1, bH, acc[1][tt], 0, 0, 0);
                acc[1][tt] = __builtin_amdgcn_mfma_f32_16x16x32_bf16(aH1, bL, acc[1][tt], 0, 0, 0);
                acc[1][tt] = __builtin_amdgcn_mfma_f32_16x16x32_bf16(aL1, bH, acc[1][tt], 0, 0, 0);
            }
        }
        #pragma unroll
        for (int tt = 0; tt < 2; ++tt) {
            const int j = (wave * 2 + tt) * 16 + nid;
            const float bb = b4[j];
            #pragma unroll
            for (int rt = 0; rt < 2; ++rt) {
                #pragma unroll
                for (int rr = 0; rr < 4; ++rr) {
                    const int row = rt * 16 + quad * 4 + rr;
                    const int orow = s_row[row];
                    if (orow >= 0) out[(size_t)orow * 128 + j] = acc[rt][tt][rr] + bb;
                }
            }
        }
    }
}

extern "C" void kernel_launch(void* const* d_in, const int* in_sizes, int n_in,
                              void* d_out, int out_size, void* d_ws, size_t ws_size,
                              hipStream_t stream) {
    const int*   seq    = (const int*)d_in[0];
    const float* xyz    = (const float*)d_in[1];
    const float* dihed  = (const float*)d_in[2];
    const int*   chain  = (const int*)d_in[3];
    const float* orient = (const float*)d_in[4];
    // d_in[5] = atom_mask: unused by the reference
    const float* aa_emb = (const float*)d_in[6];
    const float* ch_emb = (const float*)d_in[7];
    const float* W1 = (const float*)d_in[8];
    const float* b1 = (const float*)d_in[9];
    const float* W2 = (const float*)d_in[10];
    const float* b2 = (const float*)d_in[11];
    const float* W3 = (const float*)d_in[12];
    const float* b3 = (const float*)d_in[13];
    const float* W4 = (const float*)d_in[14];
    const float* b4 = (const float*)d_in[15];
    float* out = (float*)d_out;

    const int BL = in_sizes[0];           // 16384 rows

    // workspace layout
    char* p = (char*)d_ws;
    float* aaT = (float*)p;            p += 20 * 256 * 4;
    float* chT = (float*)p;            p += 10 * 256 * 4;
    int* bucket_start = (int*)p;       p += 32 * 4;
    int* blk_type     = (int*)p;       p += MAXBLK * 4;
    int* blk_chunk    = (int*)p;       p += MAXBLK * 4;
    int* rowidx       = (int*)p;       p += MAXBL * 4;
    p += ((16 - ((uintptr_t)p & 15)) & 15);
    unsigned short* W1fH = (unsigned short*)p; p += (size_t)W1F_SLOTS * 8 * 2;
    unsigned short* W1fL = (unsigned short*)p; p += (size_t)W1F_SLOTS * 8 * 2;
    unsigned short* W2fH = (unsigned short*)p; p += (size_t)W2F_SLOTS * 8 * 2;
    unsigned short* W2fL = (unsigned short*)p; p += (size_t)W2F_SLOTS * 8 * 2;
    unsigned short* W3fH = (unsigned short*)p; p += (size_t)W34F_SLOTS * 8 * 2;
    unsigned short* W3fL = (unsigned short*)p; p += (size_t)W34F_SLOTS * 8 * 2;
    unsigned short* W4fH = (unsigned short*)p; p += (size_t)W34F_SLOTS * 8 * 2;
    unsigned short* W4fL = (unsigned short*)p;

    const int nprep  = 9 + (TOT_SLOTS + 1023) / 1024;    // 77 blocks
    const int nfused = BL / TM + N_AA;                   // 532

    prep_kernel<<<nprep, 1024, 0, stream>>>(seq, aa_emb, ch_emb, W1, W2, W3, W4, BL,
                                            aaT, chT, bucket_start, blk_type, blk_chunk, rowidx,
                                            W1fH, W1fL, W2fH, W2fL, W3fH, W3fL, W4fH, W4fL);
    fused_kernel<<<nfused, 256, 0, stream>>>(chain, xyz, dihed, orient,
                                             b1, b2, b3, b4, aaT, chT,
                                             bucket_start, blk_type, blk_chunk, rowidx,
                                             W1fH, W1fL, W2fH, W2fL, W3fH, W3fL, W4fH, W4fL,
                                             out);
}